// Round 12
// baseline (351.440 us; speedup 1.0000x reference)
//
#include <hip/hip_runtime.h>

#define Bsz 1024
#define Tt  256
#define Vv  32004
#define Dd  50
#define Hh  64
#define MB  128  // vocab rows per build_tables block

typedef __bf16 b16x8 __attribute__((ext_vector_type(8)));
typedef float  f32x4 __attribute__((ext_vector_type(4)));

// barrier WITHOUT vmcnt(0) drain: LDS ordering only, in-flight global loads
// (the xw register prefetch) survive across it.
__device__ __forceinline__ void barrier_novm() {
    asm volatile("s_waitcnt lgkmcnt(0)\n\ts_barrier" ::: "memory");
}
// Fast activations via raw gfx950 opcodes (verified round 5: -46us).
__device__ __forceinline__ float fexp2(float x) {
    float r;
    asm("v_exp_f32 %0, %1" : "=v"(r) : "v"(x));
    return r;
}
__device__ __forceinline__ float frcp(float x) {
    float r;
    asm("v_rcp_f32 %0, %1" : "=v"(r) : "v"(x));
    return r;
}
// PRESCALED forms: gate pre-activations arrive already multiplied by
// -log2(e) (i,f,o) or -2*log2(e) (g) -- folded into Whh frags and tab.
__device__ __forceinline__ float fsig_p(float x)  { return frcp(1.0f + fexp2(x)); }
__device__ __forceinline__ float ftanh_p(float x) { return 2.0f * frcp(1.0f + fexp2(x)) - 1.0f; }
__device__ __forceinline__ float ftanh(float x) {
    return 2.0f * frcp(1.0f + fexp2(x * -2.885390082f)) - 1.0f;
}

// fp32 -> bf16 hi/lo split (3-term product keeps ~fp32 accuracy)
__device__ __forceinline__ void cvt_hilo(const float* x, b16x8& hi, b16x8& lo) {
#pragma unroll
    for (int e = 0; e < 8; ++e) {
        const __bf16 h = (__bf16)x[e];
        hi[e] = h;
        lo[e] = (__bf16)(x[e] - (float)h);
    }
}

// ---------------------------------------------------------------------------
// Prologue: tab[v][gate*64 + unit] = (emb[v,:].Wih[g,:] + bias) * sc[gate].
// GATE-MAJOR layout (v12): lstm_main loads one contiguous dwordx4 per gate =
// the MFMA C-fragment for its r-quad (units 16w+4q+0..3), so xw enters the
// gate sum through the MFMA accumulator instead of 4 post-MFMA VALU adds.
// Stores here become 16 scalar dwords/lane (64B-coalesced per 16-lane group).
// ---------------------------------------------------------------------------
__launch_bounds__(256)
__global__ void build_tables(const float* __restrict__ emb,
                             const float* __restrict__ Wih1,
                             const float* __restrict__ bih1,
                             const float* __restrict__ bhh1,
                             const float* __restrict__ Wih2,
                             const float* __restrict__ bih2,
                             const float* __restrict__ bhh2,
                             float* __restrict__ tab1,
                             float* __restrict__ tab2) {
    const int tid  = threadIdx.x;
    const int w    = tid >> 6;        // wave: unit tile 16w..16w+15
    const int lane = tid & 63;
    const int q    = lane >> 4;
    const int mn   = lane & 15;
    const int v0   = blockIdx.x * MB;

    const float* Wih = blockIdx.y ? Wih2 : Wih1;
    const float* bih = blockIdx.y ? bih2 : bih1;
    const float* bhh = blockIdx.y ? bhh2 : bhh1;
    float*       tab = blockIdx.y ? tab2 : tab1;

    __shared__ __align__(16) float wlds[256 * Dd];   // 51.2 KB, flat row-major
    __shared__ __align__(16) float elds[MB * Dd];    // 25.6 KB, flat row-major

    for (int d4 = tid; d4 < 256 * Dd / 4; d4 += 256)
        *(float4*)&wlds[4 * d4] = *(const float4*)(Wih + 4 * d4);
    {
        const int ebase = v0 * Dd;
        const int elim  = Vv * Dd - ebase;
        const int mx    = Vv * Dd - 1;
        for (int d4 = tid; d4 < MB * Dd / 4; d4 += 256) {
            const int d = 4 * d4;
            float4 v;
            if (d + 4 <= elim) {
                v = *(const float4*)(emb + ebase + d);
            } else {
                v.x = emb[min(ebase + d,     mx)];
                v.y = emb[min(ebase + d + 1, mx)];
                v.z = emb[min(ebase + d + 2, mx)];
                v.w = emb[min(ebase + d + 3, mx)];
            }
            *(float4*)&elds[d] = v;
        }
    }
    __syncthreads();

    b16x8 bh[4][2], bl[4][2];
    f32x4 bias4;
#pragma unroll
    for (int k = 0; k < 4; ++k) {
        const int g = 64 * k + 16 * w + mn;
        const int base = g * Dd;
        float x[8];
#pragma unroll
        for (int j = 0; j < 8; ++j) x[j] = wlds[base + 8 * q + j];
        cvt_hilo(x, bh[k][0], bl[k][0]);
#pragma unroll
        for (int j = 0; j < 8; ++j) {
            const int col = 32 + 8 * q + j;
            x[j] = (col < Dd) ? wlds[base + col] : 0.0f;
        }
        cvt_hilo(x, bh[k][1], bl[k][1]);
        bias4[k] = bih[g] + bhh[g];
    }

    // per-gate activation input scales (i,f,g,o)
    const f32x4 scale4 = {-1.442695041f, -1.442695041f, -2.885390082f, -1.442695041f};

#pragma unroll 1
    for (int m = 0; m < MB / 16; ++m) {
        const int base = (16 * m + mn) * Dd;
        b16x8 ah[2], al[2];
        float x[8];
#pragma unroll
        for (int j = 0; j < 8; ++j) x[j] = elds[base + 8 * q + j];
        cvt_hilo(x, ah[0], al[0]);
#pragma unroll
        for (int j = 0; j < 8; ++j) {
            const int col = 32 + 8 * q + j;
            x[j] = (col < Dd) ? elds[base + col] : 0.0f;
        }
        cvt_hilo(x, ah[1], al[1]);

        f32x4 acc[4];
#pragma unroll
        for (int k = 0; k < 4; ++k) {
            f32x4 a = {0.0f, 0.0f, 0.0f, 0.0f};
#pragma unroll
            for (int kh = 0; kh < 2; ++kh) {
                a = __builtin_amdgcn_mfma_f32_16x16x32_bf16(ah[kh], bh[k][kh], a, 0, 0, 0);
                a = __builtin_amdgcn_mfma_f32_16x16x32_bf16(ah[kh], bl[k][kh], a, 0, 0, 0);
                a = __builtin_amdgcn_mfma_f32_16x16x32_bf16(al[kh], bh[k][kh], a, 0, 0, 0);
            }
            acc[k] = a;
        }
        // gate-major scalar stores: tab[vr][k*64 + 16w+mn]; 16-lane groups
        // cover contiguous 64B segments per (k, q, r)
#pragma unroll
        for (int k = 0; k < 4; ++k) {
#pragma unroll
            for (int r = 0; r < 4; ++r) {
                const int vr = v0 + 16 * m + 4 * q + r;
                if (vr < Vv)
                    tab[(size_t)vr * 256 + k * 64 + 16 * w + mn] =
                        (acc[k][r] + bias4[k]) * scale4[k];
            }
        }
    }
}

// ---------------------------------------------------------------------------
// v12 recurrence == v11 structure (256 blocks x 4 rows, 4 waves, 1 unit/lane,
// in-register gates, token-register prefetch, ONE novm-barrier/step) with:
//  - xw folded into the MFMA C-operand (gate-major tab): the 4 post-MFMA
//    scalar adds vanish and pick feeds exp directly. S = 4 fat slots
//    (4 x f32x4 each): consume slot i&3, refill slot (i+2)&3 (idle since
//    step i-2 -> no WAR; distance-2 = ~1560 cyc > 900-cyc HBM latency).
//  - sel compare/cndmasks moved AFTER the barrier: they execute under the
//    next step's exposed ds_read latency.
// ---------------------------------------------------------------------------
__launch_bounds__(256, 1)
__global__ void lstm_main(const int*   __restrict__ s1,
                          const int*   __restrict__ s2,
                          const int*   __restrict__ len1,
                          const int*   __restrict__ len2,
                          const float* __restrict__ tab1,
                          const float* __restrict__ tab2,
                          const float* __restrict__ Whh1,
                          const float* __restrict__ Whh2,
                          const float* __restrict__ Wl1,
                          const float* __restrict__ bl1,
                          const float* __restrict__ Wl2,
                          const float* __restrict__ bl2,
                          float* __restrict__ out) {
    const int tid  = threadIdx.x;
    const int w    = tid >> 6;        // wave: unit tile [16w,16w+16)
    const int lane = tid & 63;
    const int q    = lane >> 4;       // MFMA quad
    const int mn   = lane & 15;       // B/C column
    const int row  = mn & 3;          // batch row within block
    const bool sb0 = (mn >> 2) & 1;   // rsel bit0
    const bool sb1 = (mn >> 3) & 1;   // rsel bit1
    const int u_own = 16 * w + 4 * q + (mn >> 2);  // this lane's hidden unit
    const int b0   = blockIdx.x * 4;

    __shared__ __align__(16) __bf16 hsh[2][4][96];  // row stride 192B: 2-way banks
    __shared__ __align__(16) int toklds[4][Tt + 8]; // per-row contiguous, padded
    __shared__ float h2s[4][64];
    __shared__ float ys[4][128];

    float c = 0.0f, selh = 0.0f, selc = 0.0f;

    for (int phase = 0; phase < 2; ++phase) {
        const float* tab  = phase ? tab2 : tab1;
        const float* Whh  = phase ? Whh2 : Whh1;
        const int*   sent = phase ? s2 : s1;
        const int*   lenp = phase ? len2 : len1;

        // stage tokens per-row contiguous (coalesced over t; one-time)
        for (int i = tid; i < 4 * Tt; i += 256)
            toklds[i >> 8][i & 255] = sent[(size_t)(b0 + (i >> 8)) * Tt + (i & 255)];

        // A fragments, PRESCALED: m-tile k (gate type) covers gates 64k+16w+0..15
        b16x8 af[8];
#pragma unroll
        for (int k = 0; k < 4; ++k) {
            const int gate = 64 * k + 16 * w + mn;
            const float sck = (k == 2) ? -2.885390082f : -1.442695041f;
#pragma unroll
            for (int kh = 0; kh < 2; ++kh) {
                const float* ar = Whh + (size_t)gate * Hh + kh * 32 + q * 8;
                const float4 f0 = *(const float4*)ar;
                const float4 f1 = *(const float4*)(ar + 4);
                b16x8 a;
                a[0] = (__bf16)(f0.x * sck); a[1] = (__bf16)(f0.y * sck);
                a[2] = (__bf16)(f0.z * sck); a[3] = (__bf16)(f0.w * sck);
                a[4] = (__bf16)(f1.x * sck); a[5] = (__bf16)(f1.y * sck);
                a[6] = (__bf16)(f1.z * sck); a[7] = (__bf16)(f1.w * sck);
                af[2 * k + kh] = a;
            }
        }

        const int mi = lenp[(size_t)(b0 + row) * Hh + u_own];

        // seed h/c (zeros phase 0, gathered state phase 1) into buffer 0
        const float h0f = phase ? selh : 0.0f;
        c = phase ? selc : 0.0f;
        hsh[0][row][u_own] = (__bf16)h0f;
        selh = 0.0f; selc = 0.0f;
        __syncthreads();

        // gate-major xw base: lane's r-quad starts at unit 16w+4q; gate k at
        // +64 floats. One addr calc + 4 imm-offset dwordx4 per refill.
        const float* tu = tab + 16 * w + 4 * q;

        // token chunks: C0=[tb..tb+3], C1=[tb+4..7], C2=[tb+8..11]
        int4 C0 = *(const int4*)&toklds[row][0];
        int4 C1 = *(const int4*)&toklds[row][4];
        int4 C2 = *(const int4*)&toklds[row][8];

        // fat S slots: SLn[k] = C-fragment for gate k (4 units x token)
        f32x4 SL0[4], SL1[4], SL2[4], SL3[4];
        auto fill = [&](f32x4 (&S)[4], int tok) {
            const float* tp = tu + (size_t)tok * 256;
            S[0] = *(const f32x4*)(tp);
            S[1] = *(const f32x4*)(tp + 64);
            S[2] = *(const f32x4*)(tp + 128);
            S[3] = *(const f32x4*)(tp + 192);
        };
        fill(SL0, C0.x);   // token tb+0
        fill(SL1, C0.y);   // token tb+1

        // select acc element rsel (2-bit, runtime) with static element indices
        auto pick = [&](const f32x4& a) -> float {
            const float e01 = sb0 ? a[1] : a[0];
            const float e23 = sb0 ? a[3] : a[2];
            return sb1 ? e23 : e01;
        };

        // step i: consume slot i&3 (token tb+i), refill slot (i+2)&3 (tb+i+2)
        auto step = [&](int i, f32x4 (&Su)[4], f32x4 (&Sf)[4], int tok, int tb) {
            fill(Sf, tok);   // no dependence on this step's compute

            const int rb = i & 1, wb = rb ^ 1;
            const b16x8 bf0 = *(const b16x8*)&hsh[rb][row][q * 8];
            const b16x8 bf1 = *(const b16x8*)&hsh[rb][row][32 + q * 8];

            // xw rides the C operand; order g,i,f,o (tanh chain longest)
            f32x4 aG = __builtin_amdgcn_mfma_f32_16x16x32_bf16(af[4], bf0, Su[2], 0, 0, 0);
            aG = __builtin_amdgcn_mfma_f32_16x16x32_bf16(af[5], bf1, aG, 0, 0, 0);
            f32x4 aI = __builtin_amdgcn_mfma_f32_16x16x32_bf16(af[0], bf0, Su[0], 0, 0, 0);
            aI = __builtin_amdgcn_mfma_f32_16x16x32_bf16(af[1], bf1, aI, 0, 0, 0);
            f32x4 aF = __builtin_amdgcn_mfma_f32_16x16x32_bf16(af[2], bf0, Su[1], 0, 0, 0);
            aF = __builtin_amdgcn_mfma_f32_16x16x32_bf16(af[3], bf1, aF, 0, 0, 0);
            f32x4 aO = __builtin_amdgcn_mfma_f32_16x16x32_bf16(af[6], bf0, Su[3], 0, 0, 0);
            aO = __builtin_amdgcn_mfma_f32_16x16x32_bf16(af[7], bf1, aO, 0, 0, 0);

            const float gv = ftanh_p(pick(aG));
            const float iv = fsig_p(pick(aI));
            const float fv = fsig_p(pick(aF));
            const float ov = fsig_p(pick(aO));
            c = fv * c + iv * gv;
            const float hv = ov * ftanh(c);
            hsh[wb][row][u_own] = (__bf16)hv;
            barrier_novm();   // ONE barrier/step; prefetch stays in flight
            if (tb + i == mi) { selh = hv; selc = c; }  // under next ds_read
        };

        for (int tb = 0; tb < Tt; tb += 8) {
            step(0, SL0, SL2, C0.z, tb);
            step(1, SL1, SL3, C0.w, tb);
            // next-iteration token chunks (ds_read latency hidden under steps)
            const int nb1 = min(tb + 12, Tt - 4);
            const int4 N1 = *(const int4*)&toklds[row][nb1];
            step(2, SL2, SL0, C1.x, tb);
            const int nb2 = min(tb + 16, Tt - 4);
            const int4 N2 = *(const int4*)&toklds[row][nb2];
            step(3, SL3, SL1, C1.y, tb);
            step(4, SL0, SL2, C1.z, tb);
            step(5, SL1, SL3, C1.w, tb);
            step(6, SL2, SL0, C2.x, tb);
            step(7, SL3, SL1, C2.y, tb);
            C0 = C2; C1 = N1; C2 = N2;
        }
    }

    // ---------------- epilogue MLP on the 4 gathered rows -------------------
    h2s[row][u_own] = selh;
    __syncthreads();
#pragma unroll
    for (int p = 0; p < 2; ++p) {
        const int idx = tid + 256 * p;        // 512 (row, neuron) tasks
        const int rr = idx >> 7, n = idx & 127;
        float a = bl1[n];
        const float* wl = Wl1 + n * 64;
#pragma unroll 8
        for (int k = 0; k < 64; ++k) a += h2s[rr][k] * wl[k];
        ys[rr][n] = ftanh(a);
    }
    __syncthreads();
    if (tid < 16) {
        const int rr = tid >> 2, o = tid & 3;
        float a = bl2[o];
        const float* wl = Wl2 + o * 128;
#pragma unroll 8
        for (int k = 0; k < 128; ++k) a += ys[rr][k] * wl[k];
        out[(size_t)(b0 + rr) * 4 + o] = a;
    }
}

// ---------------------------------------------------------------------------
extern "C" void kernel_launch(void* const* d_in, const int* in_sizes, int n_in,
                              void* d_out, int out_size, void* d_ws, size_t ws_size,
                              hipStream_t stream) {
    const int*   s1   = (const int*)d_in[0];
    const int*   s2   = (const int*)d_in[1];
    const int*   l1   = (const int*)d_in[2];
    const int*   l2   = (const int*)d_in[3];
    // d_in[4], d_in[5] (s1_s, s2_s) unused by the reference
    const float* emb  = (const float*)d_in[6];
    const float* Wih1 = (const float*)d_in[7];
    const float* Whh1 = (const float*)d_in[8];
    const float* bih1 = (const float*)d_in[9];
    const float* bhh1 = (const float*)d_in[10];
    const float* Wih2 = (const float*)d_in[11];
    const float* Whh2 = (const float*)d_in[12];
    const float* bih2 = (const float*)d_in[13];
    const float* bhh2 = (const float*)d_in[14];
    const float* Wl1  = (const float*)d_in[15];
    const float* bl1  = (const float*)d_in[16];
    const float* Wl2  = (const float*)d_in[17];
    const float* bl2  = (const float*)d_in[18];
    float* out = (float*)d_out;

    float* tab1 = (float*)d_ws;                       // [V,256] fp32, gate-major
    float* tab2 = tab1 + (size_t)Vv * 256;            // [V,256] fp32  (65.6 MB)

    dim3 grid((Vv + MB - 1) / MB, 2);
    build_tables<<<grid, 256, 0, stream>>>(emb, Wih1, bih1, bhh1,
                                           Wih2, bih2, bhh2, tab1, tab2);
    lstm_main<<<Bsz / 4, 256, 0, stream>>>(s1, s2, l1, l2, tab1, tab2,
                                           Whh1, Whh2, Wl1, bl1, Wl2, bl2, out);
}

// Round 13
// 259.367 us; speedup vs baseline: 1.3550x; 1.3550x over previous
//
#include <hip/hip_runtime.h>

#define Bsz 1024
#define Tt  256
#define Vv  32004
#define Dd  50
#define Hh  64
#define MB  128  // vocab rows per build_tables block

typedef __bf16 b16x8 __attribute__((ext_vector_type(8)));
typedef float  f32x4 __attribute__((ext_vector_type(4)));

// barrier WITHOUT vmcnt(0) drain: LDS ordering only, in-flight global loads
// (the xw register prefetch) survive across it.
__device__ __forceinline__ void barrier_novm() {
    asm volatile("s_waitcnt lgkmcnt(0)\n\ts_barrier" ::: "memory");
}
// Fast activations via raw gfx950 opcodes (verified round 5: -46us).
__device__ __forceinline__ float fexp2(float x) {
    float r;
    asm("v_exp_f32 %0, %1" : "=v"(r) : "v"(x));
    return r;
}
__device__ __forceinline__ float frcp(float x) {
    float r;
    asm("v_rcp_f32 %0, %1" : "=v"(r) : "v"(x));
    return r;
}
// PRESCALED forms: gate pre-activations arrive already multiplied by
// -log2(e) (i,f,o) or -2*log2(e) (g) -- folded into Whh frags and tab.
__device__ __forceinline__ float fsig_p(float x)  { return frcp(1.0f + fexp2(x)); }
__device__ __forceinline__ float ftanh_p(float x) { return 2.0f * frcp(1.0f + fexp2(x)) - 1.0f; }
__device__ __forceinline__ float ftanh(float x) {
    return 2.0f * frcp(1.0f + fexp2(x * -2.885390082f)) - 1.0f;
}

// fp32 -> bf16 hi/lo split (3-term product keeps ~fp32 accuracy)
__device__ __forceinline__ void cvt_hilo(const float* x, b16x8& hi, b16x8& lo) {
#pragma unroll
    for (int e = 0; e < 8; ++e) {
        const __bf16 h = (__bf16)x[e];
        hi[e] = h;
        lo[e] = (__bf16)(x[e] - (float)h);
    }
}

// ---------------------------------------------------------------------------
// Prologue: tab[v][unit*4+gate] = (emb[v,:].Wih[g,:] + bias) * sc[gate].
// UNIT-MAJOR layout (v11 form, reverted from v12's gate-major): lstm_main
// reads one dwordx4 per (token, unit) and adds xw AFTER the MFMAs -- keeping
// loads out of MFMA operands so the compiler's vmcnt wait lands post-MFMA
// (v12 lesson: loaded C-operand => conservative vmcnt drain at the step head,
// +450 cyc stall).
// ---------------------------------------------------------------------------
__launch_bounds__(256)
__global__ void build_tables(const float* __restrict__ emb,
                             const float* __restrict__ Wih1,
                             const float* __restrict__ bih1,
                             const float* __restrict__ bhh1,
                             const float* __restrict__ Wih2,
                             const float* __restrict__ bih2,
                             const float* __restrict__ bhh2,
                             float* __restrict__ tab1,
                             float* __restrict__ tab2) {
    const int tid  = threadIdx.x;
    const int w    = tid >> 6;        // wave: unit tile 16w..16w+15
    const int lane = tid & 63;
    const int q    = lane >> 4;
    const int mn   = lane & 15;
    const int v0   = blockIdx.x * MB;

    const float* Wih = blockIdx.y ? Wih2 : Wih1;
    const float* bih = blockIdx.y ? bih2 : bih1;
    const float* bhh = blockIdx.y ? bhh2 : bhh1;
    float*       tab = blockIdx.y ? tab2 : tab1;

    __shared__ __align__(16) float wlds[256 * Dd];   // 51.2 KB, flat row-major
    __shared__ __align__(16) float elds[MB * Dd];    // 25.6 KB, flat row-major

    for (int d4 = tid; d4 < 256 * Dd / 4; d4 += 256)
        *(float4*)&wlds[4 * d4] = *(const float4*)(Wih + 4 * d4);
    {
        const int ebase = v0 * Dd;
        const int elim  = Vv * Dd - ebase;
        const int mx    = Vv * Dd - 1;
        for (int d4 = tid; d4 < MB * Dd / 4; d4 += 256) {
            const int d = 4 * d4;
            float4 v;
            if (d + 4 <= elim) {
                v = *(const float4*)(emb + ebase + d);
            } else {
                v.x = emb[min(ebase + d,     mx)];
                v.y = emb[min(ebase + d + 1, mx)];
                v.z = emb[min(ebase + d + 2, mx)];
                v.w = emb[min(ebase + d + 3, mx)];
            }
            *(float4*)&elds[d] = v;
        }
    }
    __syncthreads();

    b16x8 bh[4][2], bl[4][2];
    f32x4 bias4;
#pragma unroll
    for (int k = 0; k < 4; ++k) {
        const int g = 64 * k + 16 * w + mn;
        const int base = g * Dd;
        float x[8];
#pragma unroll
        for (int j = 0; j < 8; ++j) x[j] = wlds[base + 8 * q + j];
        cvt_hilo(x, bh[k][0], bl[k][0]);
#pragma unroll
        for (int j = 0; j < 8; ++j) {
            const int col = 32 + 8 * q + j;
            x[j] = (col < Dd) ? wlds[base + col] : 0.0f;
        }
        cvt_hilo(x, bh[k][1], bl[k][1]);
        bias4[k] = bih[g] + bhh[g];
    }

    // per-gate activation input scales (i,f,g,o)
    const f32x4 scale4 = {-1.442695041f, -1.442695041f, -2.885390082f, -1.442695041f};

#pragma unroll 1
    for (int m = 0; m < MB / 16; ++m) {
        const int base = (16 * m + mn) * Dd;
        b16x8 ah[2], al[2];
        float x[8];
#pragma unroll
        for (int j = 0; j < 8; ++j) x[j] = elds[base + 8 * q + j];
        cvt_hilo(x, ah[0], al[0]);
#pragma unroll
        for (int j = 0; j < 8; ++j) {
            const int col = 32 + 8 * q + j;
            x[j] = (col < Dd) ? elds[base + col] : 0.0f;
        }
        cvt_hilo(x, ah[1], al[1]);

        f32x4 acc[4];
#pragma unroll
        for (int k = 0; k < 4; ++k) {
            f32x4 a = {0.0f, 0.0f, 0.0f, 0.0f};
#pragma unroll
            for (int kh = 0; kh < 2; ++kh) {
                a = __builtin_amdgcn_mfma_f32_16x16x32_bf16(ah[kh], bh[k][kh], a, 0, 0, 0);
                a = __builtin_amdgcn_mfma_f32_16x16x32_bf16(ah[kh], bl[k][kh], a, 0, 0, 0);
                a = __builtin_amdgcn_mfma_f32_16x16x32_bf16(al[kh], bh[k][kh], a, 0, 0, 0);
            }
            acc[k] = a;
        }
#pragma unroll
        for (int r = 0; r < 4; ++r) {
            const int vr = v0 + 16 * m + 4 * q + r;
            if (vr < Vv) {
                f32x4 o;
                o[0] = (acc[0][r] + bias4[0]) * scale4[0];
                o[1] = (acc[1][r] + bias4[1]) * scale4[1];
                o[2] = (acc[2][r] + bias4[2]) * scale4[2];
                o[3] = (acc[3][r] + bias4[3]) * scale4[3];
                *(f32x4*)(tab + (size_t)vr * 256 + (16 * w + mn) * 4) = o;
            }
        }
    }
}

// ---------------------------------------------------------------------------
// v13 recurrence == v11 (verified 166.7us: 256 blocks x 4 rows, 4 waves,
// 1 unit/lane, in-register gates, token-register prefetch, 8-slot distance-4
// S rotation with in-place WAR refill AFTER the consuming adds, prescaled
// activations, ONE novm-barrier/step) + one micro-trim from v12's bundle:
// the sel compare/cndmasks execute AFTER the barrier, in the shadow of the
// next step's ds_read latency.
// Structural map (all falsified alternatives): v8-shape 790 cyc/step <
// v10 dual-group 1253 < v9 wave-solo 1608; v6/v12 prefetch re-plumbings both
// exposed load latency at the step head (+60 / +450 cyc).
// ---------------------------------------------------------------------------
__launch_bounds__(256, 1)
__global__ void lstm_main(const int*   __restrict__ s1,
                          const int*   __restrict__ s2,
                          const int*   __restrict__ len1,
                          const int*   __restrict__ len2,
                          const float* __restrict__ tab1,
                          const float* __restrict__ tab2,
                          const float* __restrict__ Whh1,
                          const float* __restrict__ Whh2,
                          const float* __restrict__ Wl1,
                          const float* __restrict__ bl1,
                          const float* __restrict__ Wl2,
                          const float* __restrict__ bl2,
                          float* __restrict__ out) {
    const int tid  = threadIdx.x;
    const int w    = tid >> 6;        // wave: unit tile [16w,16w+16)
    const int lane = tid & 63;
    const int q    = lane >> 4;       // MFMA quad
    const int mn   = lane & 15;       // B/C column
    const int row  = mn & 3;          // batch row within block
    const bool sb0 = (mn >> 2) & 1;   // rsel bit0
    const bool sb1 = (mn >> 3) & 1;   // rsel bit1
    const int u_own = 16 * w + 4 * q + (mn >> 2);  // this lane's hidden unit
    const int b0   = blockIdx.x * 4;

    __shared__ __align__(16) __bf16 hsh[2][4][96];  // row stride 192B: 2-way banks
    __shared__ __align__(16) int toklds[4][Tt + 8]; // per-row contiguous, padded
    __shared__ float h2s[4][64];
    __shared__ float ys[4][128];

    float c = 0.0f, selh = 0.0f, selc = 0.0f;
    const f32x4 zero4 = {0.0f, 0.0f, 0.0f, 0.0f};

    for (int phase = 0; phase < 2; ++phase) {
        const float* tab  = phase ? tab2 : tab1;
        const float* Whh  = phase ? Whh2 : Whh1;
        const int*   sent = phase ? s2 : s1;
        const int*   lenp = phase ? len2 : len1;

        // stage tokens per-row contiguous (coalesced over t; one-time)
        for (int i = tid; i < 4 * Tt; i += 256)
            toklds[i >> 8][i & 255] = sent[(size_t)(b0 + (i >> 8)) * Tt + (i & 255)];

        // A fragments, PRESCALED: m-tile k (gate type) covers gates 64k+16w+0..15
        b16x8 af[8];
#pragma unroll
        for (int k = 0; k < 4; ++k) {
            const int gate = 64 * k + 16 * w + mn;
            const float sck = (k == 2) ? -2.885390082f : -1.442695041f;
#pragma unroll
            for (int kh = 0; kh < 2; ++kh) {
                const float* ar = Whh + (size_t)gate * Hh + kh * 32 + q * 8;
                const float4 f0 = *(const float4*)ar;
                const float4 f1 = *(const float4*)(ar + 4);
                b16x8 a;
                a[0] = (__bf16)(f0.x * sck); a[1] = (__bf16)(f0.y * sck);
                a[2] = (__bf16)(f0.z * sck); a[3] = (__bf16)(f0.w * sck);
                a[4] = (__bf16)(f1.x * sck); a[5] = (__bf16)(f1.y * sck);
                a[6] = (__bf16)(f1.z * sck); a[7] = (__bf16)(f1.w * sck);
                af[2 * k + kh] = a;
            }
        }

        const int mi = lenp[(size_t)(b0 + row) * Hh + u_own];

        // seed h/c (zeros phase 0, gathered state phase 1) into buffer 0
        const float h0f = phase ? selh : 0.0f;
        c = phase ? selc : 0.0f;
        hsh[0][row][u_own] = (__bf16)h0f;
        selh = 0.0f; selc = 0.0f;
        __syncthreads();

        const float* tu = tab + 4 * u_own;

        // token register chunks: tkA = tokens[tb+4..7], tkB = tokens[tb+8..11]
        int4 tk0 = *(const int4*)&toklds[row][0];
        int4 tkA = *(const int4*)&toklds[row][4];
        int4 tkB = *(const int4*)&toklds[row][8];

        // prime S slots 0..3 (t=0..3); slots 4..7 are filled during steps 0..3
        f32x4 S0, S1, S2, S3, S4, S5, S6, S7;
        S0 = *(const f32x4*)(tu + (size_t)tk0.x * 256);
        S1 = *(const f32x4*)(tu + (size_t)tk0.y * 256);
        S2 = *(const f32x4*)(tu + (size_t)tk0.z * 256);
        S3 = *(const f32x4*)(tu + (size_t)tk0.w * 256);

        // select acc element rsel (2-bit, runtime) with static element indices
        auto pick = [&](const f32x4& a) -> float {
            const float e01 = sb0 ? a[1] : a[0];
            const float e23 = sb0 ? a[3] : a[2];
            return sb1 ? e23 : e01;
        };

        // step i: consume Su (slot i), refill Sf (slot (i+4)&7) with token tok
        auto step = [&](int i, f32x4& Su, f32x4& Sf, int tok, int tb) {
            // refill FIRST: register token -> address ready, no compute dep,
            // load issues at step start; consumed slot Su untouched.
            Sf = *(const f32x4*)(tu + (size_t)tok * 256);

            const int rb = i & 1, wb = rb ^ 1;
            const b16x8 bf0 = *(const b16x8*)&hsh[rb][row][q * 8];
            const b16x8 bf1 = *(const b16x8*)&hsh[rb][row][32 + q * 8];

            // order g,i,f,o: tanh(gG) is the longest dependent chain
            f32x4 aG = __builtin_amdgcn_mfma_f32_16x16x32_bf16(af[4], bf0, zero4, 0, 0, 0);
            aG = __builtin_amdgcn_mfma_f32_16x16x32_bf16(af[5], bf1, aG, 0, 0, 0);
            f32x4 aI = __builtin_amdgcn_mfma_f32_16x16x32_bf16(af[0], bf0, zero4, 0, 0, 0);
            aI = __builtin_amdgcn_mfma_f32_16x16x32_bf16(af[1], bf1, aI, 0, 0, 0);
            f32x4 aF = __builtin_amdgcn_mfma_f32_16x16x32_bf16(af[2], bf0, zero4, 0, 0, 0);
            aF = __builtin_amdgcn_mfma_f32_16x16x32_bf16(af[3], bf1, aF, 0, 0, 0);
            f32x4 aO = __builtin_amdgcn_mfma_f32_16x16x32_bf16(af[6], bf0, zero4, 0, 0, 0);
            aO = __builtin_amdgcn_mfma_f32_16x16x32_bf16(af[7], bf1, aO, 0, 0, 0);

            const float gG = pick(aG) + Su[2];
            const float gI = pick(aI) + Su[0];
            const float gF = pick(aF) + Su[1];
            const float gO = pick(aO) + Su[3];
            // refill S for t+4 IN PLACE (WAR): issue after the consuming adds,
            // vmcnt wait deferred to S's use 4 steps out = full distance-4
            Su = *(const f32x4*)(tu + (size_t)toklds[row][0] * 256); // placeholder never used
            (void)Su;
            const float gv = ftanh_p(gG);
            const float iv = fsig_p(gI);
            const float fv = fsig_p(gF);
            const float ov = fsig_p(gO);
            c = fv * c + iv * gv;
            const float hv = ov * ftanh(c);
            hsh[wb][row][u_own] = (__bf16)hv;   // write first: off the tail
            barrier_novm();   // ONE barrier/step; global prefetch stays in flight
            if (tb + i == mi) { selh = hv; selc = c; }  // under next ds_read
        };
        // NOTE: the placeholder write above is WRONG -- see corrected step
        // below; kept structure identical to v11 (refill Sf at head, no
        // in-place Su refill).
        (void)step;

        auto step2 = [&](int i, f32x4& Su, f32x4& Sf, int tok, int tb) {
            Sf = *(const f32x4*)(tu + (size_t)tok * 256);

            const int rb = i & 1, wb = rb ^ 1;
            const b16x8 bf0 = *(const b16x8*)&hsh[rb][row][q * 8];
            const b16x8 bf1 = *(const b16x8*)&hsh[rb][row][32 + q * 8];

            f32x4 aG = __builtin_amdgcn_mfma_f32_16x16x32_bf16(af[4], bf0, zero4, 0, 0, 0);
            aG = __builtin_amdgcn_mfma_f32_16x16x32_bf16(af[5], bf1, aG, 0, 0, 0);
            f32x4 aI = __builtin_amdgcn_mfma_f32_16x16x32_bf16(af[0], bf0, zero4, 0, 0, 0);
            aI = __builtin_amdgcn_mfma_f32_16x16x32_bf16(af[1], bf1, aI, 0, 0, 0);
            f32x4 aF = __builtin_amdgcn_mfma_f32_16x16x32_bf16(af[2], bf0, zero4, 0, 0, 0);
            aF = __builtin_amdgcn_mfma_f32_16x16x32_bf16(af[3], bf1, aF, 0, 0, 0);
            f32x4 aO = __builtin_amdgcn_mfma_f32_16x16x32_bf16(af[6], bf0, zero4, 0, 0, 0);
            aO = __builtin_amdgcn_mfma_f32_16x16x32_bf16(af[7], bf1, aO, 0, 0, 0);

            const float gG = pick(aG) + Su[2];
            const float gI = pick(aI) + Su[0];
            const float gF = pick(aF) + Su[1];
            const float gO = pick(aO) + Su[3];

            const float gv = ftanh_p(gG);
            const float iv = fsig_p(gI);
            const float fv = fsig_p(gF);
            const float ov = fsig_p(gO);
            c = fv * c + iv * gv;
            const float hv = ov * ftanh(c);
            hsh[wb][row][u_own] = (__bf16)hv;   // write first: off the tail
            barrier_novm();   // ONE barrier/step; global prefetch stays in flight
            if (tb + i == mi) { selh = hv; selc = c; }  // under next ds_read
        };

        for (int tb = 0; tb < Tt; tb += 8) {
            step2(0, S0, S4, tkA.x, tb);
            step2(1, S1, S5, tkA.y, tb);
            // next-iteration token chunks (ds_read latency hidden under steps)
            const int nb1 = min(tb + 12, Tt - 4);
            const int4 tA2 = *(const int4*)&toklds[row][nb1];
            step2(2, S2, S6, tkA.z, tb);
            const int nb2 = min(tb + 16, Tt - 4);
            const int4 tB2 = *(const int4*)&toklds[row][nb2];
            step2(3, S3, S7, tkA.w, tb);
            step2(4, S4, S0, tkB.x, tb);
            step2(5, S5, S1, tkB.y, tb);
            step2(6, S6, S2, tkB.z, tb);
            step2(7, S7, S3, tkB.w, tb);
            tkA = tA2; tkB = tB2;
        }
    }

    // ---------------- epilogue MLP on the 4 gathered rows -------------------
    h2s[row][u_own] = selh;
    __syncthreads();
#pragma unroll
    for (int p = 0; p < 2; ++p) {
        const int idx = tid + 256 * p;        // 512 (row, neuron) tasks
        const int rr = idx >> 7, n = idx & 127;
        float a = bl1[n];
        const float* wl = Wl1 + n * 64;
#pragma unroll 8
        for (int k = 0; k < 64; ++k) a += h2s[rr][k] * wl[k];
        ys[rr][n] = ftanh(a);
    }
    __syncthreads();
    if (tid < 16) {
        const int rr = tid >> 2, o = tid & 3;
        float a = bl2[o];
        const float* wl = Wl2 + o * 128;
#pragma unroll 8
        for (int k = 0; k < 128; ++k) a += ys[rr][k] * wl[k];
        out[(size_t)(b0 + rr) * 4 + o] = a;
    }
}

// ---------------------------------------------------------------------------
extern "C" void kernel_launch(void* const* d_in, const int* in_sizes, int n_in,
                              void* d_out, int out_size, void* d_ws, size_t ws_size,
                              hipStream_t stream) {
    const int*   s1   = (const int*)d_in[0];
    const int*   s2   = (const int*)d_in[1];
    const int*   l1   = (const int*)d_in[2];
    const int*   l2   = (const int*)d_in[3];
    // d_in[4], d_in[5] (s1_s, s2_s) unused by the reference
    const float* emb  = (const float*)d_in[6];
    const float* Wih1 = (const float*)d_in[7];
    const float* Whh1 = (const float*)d_in[8];
    const float* bih1 = (const float*)d_in[9];
    const float* bhh1 = (const float*)d_in[10];
    const float* Wih2 = (const float*)d_in[11];
    const float* Whh2 = (const float*)d_in[12];
    const float* bih2 = (const float*)d_in[13];
    const float* bhh2 = (const float*)d_in[14];
    const float* Wl1  = (const float*)d_in[15];
    const float* bl1  = (const float*)d_in[16];
    const float* Wl2  = (const float*)d_in[17];
    const float* bl2  = (const float*)d_in[18];
    float* out = (float*)d_out;

    float* tab1 = (float*)d_ws;                       // [V,256] fp32, unit-major
    float* tab2 = tab1 + (size_t)Vv * 256;            // [V,256] fp32  (65.6 MB)

    dim3 grid((Vv + MB - 1) / MB, 2);
    build_tables<<<grid, 256, 0, stream>>>(emb, Wih1, bih1, bhh1,
                                           Wih2, bih2, bhh2, tab1, tab2);
    lstm_main<<<Bsz / 4, 256, 0, stream>>>(s1, s2, l1, l2, tab1, tab2,
                                           Whh1, Whh2, Wl1, bl1, Wl2, bl2, out);
}

// Round 14
// 257.892 us; speedup vs baseline: 1.3627x; 1.0057x over previous
//
#include <hip/hip_runtime.h>

#define Bsz 1024
#define Tt  256
#define Vv  32004
#define Dd  50
#define Hh  64
#define MB  128  // vocab rows per build_tables block

typedef __bf16 b16x8 __attribute__((ext_vector_type(8)));
typedef float  f32x4 __attribute__((ext_vector_type(4)));

// barrier WITHOUT vmcnt(0) drain: LDS ordering only, in-flight global loads
// (the xw register prefetch) survive across it.
__device__ __forceinline__ void barrier_novm() {
    asm volatile("s_waitcnt lgkmcnt(0)\n\ts_barrier" ::: "memory");
}
// Fast activations via raw gfx950 opcodes (verified round 5: -46us).
__device__ __forceinline__ float fexp2(float x) {
    float r;
    asm("v_exp_f32 %0, %1" : "=v"(r) : "v"(x));
    return r;
}
__device__ __forceinline__ float frcp(float x) {
    float r;
    asm("v_rcp_f32 %0, %1" : "=v"(r) : "v"(x));
    return r;
}
// PRESCALED forms: gate pre-activations arrive already multiplied by
// -log2(e) (i,f,o) or -2*log2(e) (g) -- folded into Whh frags and tab.
__device__ __forceinline__ float fsig_p(float x)  { return frcp(1.0f + fexp2(x)); }
__device__ __forceinline__ float ftanh(float x) {
    return 2.0f * frcp(1.0f + fexp2(x * -2.885390082f)) - 1.0f;
}

// fp32 -> bf16 hi/lo split (3-term product keeps ~fp32 accuracy)
__device__ __forceinline__ void cvt_hilo(const float* x, b16x8& hi, b16x8& lo) {
#pragma unroll
    for (int e = 0; e < 8; ++e) {
        const __bf16 h = (__bf16)x[e];
        hi[e] = h;
        lo[e] = (__bf16)(x[e] - (float)h);
    }
}

// ---------------------------------------------------------------------------
// Prologue: tab[v][unit*4+gate] = (emb[v,:].Wih[g,:] + bias) * sc[gate].
// UNIT-MAJOR layout: lstm_main reads one dwordx4 per (token, unit) and adds
// xw AFTER the MFMAs -- keeping loads out of MFMA operands so the compiler's
// vmcnt wait lands post-MFMA (v12 lesson: loaded C-operand => conservative
// vmcnt drain at the step head, +450 cyc stall).
// ---------------------------------------------------------------------------
__launch_bounds__(256)
__global__ void build_tables(const float* __restrict__ emb,
                             const float* __restrict__ Wih1,
                             const float* __restrict__ bih1,
                             const float* __restrict__ bhh1,
                             const float* __restrict__ Wih2,
                             const float* __restrict__ bih2,
                             const float* __restrict__ bhh2,
                             float* __restrict__ tab1,
                             float* __restrict__ tab2) {
    const int tid  = threadIdx.x;
    const int w    = tid >> 6;        // wave: unit tile 16w..16w+15
    const int lane = tid & 63;
    const int q    = lane >> 4;
    const int mn   = lane & 15;
    const int v0   = blockIdx.x * MB;

    const float* Wih = blockIdx.y ? Wih2 : Wih1;
    const float* bih = blockIdx.y ? bih2 : bih1;
    const float* bhh = blockIdx.y ? bhh2 : bhh1;
    float*       tab = blockIdx.y ? tab2 : tab1;

    __shared__ __align__(16) float wlds[256 * Dd];   // 51.2 KB, flat row-major
    __shared__ __align__(16) float elds[MB * Dd];    // 25.6 KB, flat row-major

    for (int d4 = tid; d4 < 256 * Dd / 4; d4 += 256)
        *(float4*)&wlds[4 * d4] = *(const float4*)(Wih + 4 * d4);
    {
        const int ebase = v0 * Dd;
        const int elim  = Vv * Dd - ebase;
        const int mx    = Vv * Dd - 1;
        for (int d4 = tid; d4 < MB * Dd / 4; d4 += 256) {
            const int d = 4 * d4;
            float4 v;
            if (d + 4 <= elim) {
                v = *(const float4*)(emb + ebase + d);
            } else {
                v.x = emb[min(ebase + d,     mx)];
                v.y = emb[min(ebase + d + 1, mx)];
                v.z = emb[min(ebase + d + 2, mx)];
                v.w = emb[min(ebase + d + 3, mx)];
            }
            *(float4*)&elds[d] = v;
        }
    }
    __syncthreads();

    b16x8 bh[4][2], bl[4][2];
    f32x4 bias4;
#pragma unroll
    for (int k = 0; k < 4; ++k) {
        const int g = 64 * k + 16 * w + mn;
        const int base = g * Dd;
        float x[8];
#pragma unroll
        for (int j = 0; j < 8; ++j) x[j] = wlds[base + 8 * q + j];
        cvt_hilo(x, bh[k][0], bl[k][0]);
#pragma unroll
        for (int j = 0; j < 8; ++j) {
            const int col = 32 + 8 * q + j;
            x[j] = (col < Dd) ? wlds[base + col] : 0.0f;
        }
        cvt_hilo(x, bh[k][1], bl[k][1]);
        bias4[k] = bih[g] + bhh[g];
    }

    // per-gate activation input scales (i,f,g,o)
    const f32x4 scale4 = {-1.442695041f, -1.442695041f, -2.885390082f, -1.442695041f};

#pragma unroll 1
    for (int m = 0; m < MB / 16; ++m) {
        const int base = (16 * m + mn) * Dd;
        b16x8 ah[2], al[2];
        float x[8];
#pragma unroll
        for (int j = 0; j < 8; ++j) x[j] = elds[base + 8 * q + j];
        cvt_hilo(x, ah[0], al[0]);
#pragma unroll
        for (int j = 0; j < 8; ++j) {
            const int col = 32 + 8 * q + j;
            x[j] = (col < Dd) ? elds[base + col] : 0.0f;
        }
        cvt_hilo(x, ah[1], al[1]);

        f32x4 acc[4];
#pragma unroll
        for (int k = 0; k < 4; ++k) {
            f32x4 a = {0.0f, 0.0f, 0.0f, 0.0f};
#pragma unroll
            for (int kh = 0; kh < 2; ++kh) {
                a = __builtin_amdgcn_mfma_f32_16x16x32_bf16(ah[kh], bh[k][kh], a, 0, 0, 0);
                a = __builtin_amdgcn_mfma_f32_16x16x32_bf16(ah[kh], bl[k][kh], a, 0, 0, 0);
                a = __builtin_amdgcn_mfma_f32_16x16x32_bf16(al[kh], bh[k][kh], a, 0, 0, 0);
            }
            acc[k] = a;
        }
#pragma unroll
        for (int r = 0; r < 4; ++r) {
            const int vr = v0 + 16 * m + 4 * q + r;
            if (vr < Vv) {
                f32x4 o;
                o[0] = (acc[0][r] + bias4[0]) * scale4[0];
                o[1] = (acc[1][r] + bias4[1]) * scale4[1];
                o[2] = (acc[2][r] + bias4[2]) * scale4[2];
                o[3] = (acc[3][r] + bias4[3]) * scale4[3];
                *(f32x4*)(tab + (size_t)vr * 256 + (16 * w + mn) * 4) = o;
            }
        }
    }
}

// ---------------------------------------------------------------------------
// v14 recurrence == v13 (verified ~164us: 256 blocks x 4 rows, 4 waves,
// 1 unit/lane, in-register gates, token-register prefetch, 8-slot distance-4
// S rotation, prescaled activations, ONE novm-barrier/step, sel after the
// barrier) + scaled-c shadow accumulator: cs = -2log2(e)*c is maintained in
// parallel (gvs/ivgvs off the critical chain), so tanh(c) starts directly at
// exp2(cs) -- the dependent mul is deleted from the longest chain.
// Structural map (falsified alternatives): v8-shape 765 cyc/step < v10
// dual-group 1253 < v9 wave-solo 1608; v6/v12 prefetch re-plumbings exposed
// load latency at the step head (+60 / +450 cyc).
// ---------------------------------------------------------------------------
__launch_bounds__(256, 1)
__global__ void lstm_main(const int*   __restrict__ s1,
                          const int*   __restrict__ s2,
                          const int*   __restrict__ len1,
                          const int*   __restrict__ len2,
                          const float* __restrict__ tab1,
                          const float* __restrict__ tab2,
                          const float* __restrict__ Whh1,
                          const float* __restrict__ Whh2,
                          const float* __restrict__ Wl1,
                          const float* __restrict__ bl1,
                          const float* __restrict__ Wl2,
                          const float* __restrict__ bl2,
                          float* __restrict__ out) {
    const int tid  = threadIdx.x;
    const int w    = tid >> 6;        // wave: unit tile [16w,16w+16)
    const int lane = tid & 63;
    const int q    = lane >> 4;       // MFMA quad
    const int mn   = lane & 15;       // B/C column
    const int row  = mn & 3;          // batch row within block
    const bool sb0 = (mn >> 2) & 1;   // rsel bit0
    const bool sb1 = (mn >> 3) & 1;   // rsel bit1
    const int u_own = 16 * w + 4 * q + (mn >> 2);  // this lane's hidden unit
    const int b0   = blockIdx.x * 4;

    __shared__ __align__(16) __bf16 hsh[2][4][96];  // row stride 192B: 2-way banks
    __shared__ __align__(16) int toklds[4][Tt + 8]; // per-row contiguous, padded
    __shared__ float h2s[4][64];
    __shared__ float ys[4][128];

    float c = 0.0f, cs = 0.0f, selh = 0.0f, selc = 0.0f;
    const f32x4 zero4 = {0.0f, 0.0f, 0.0f, 0.0f};

    for (int phase = 0; phase < 2; ++phase) {
        const float* tab  = phase ? tab2 : tab1;
        const float* Whh  = phase ? Whh2 : Whh1;
        const int*   sent = phase ? s2 : s1;
        const int*   lenp = phase ? len2 : len1;

        // stage tokens per-row contiguous (coalesced over t; one-time)
        for (int i = tid; i < 4 * Tt; i += 256)
            toklds[i >> 8][i & 255] = sent[(size_t)(b0 + (i >> 8)) * Tt + (i & 255)];

        // A fragments, PRESCALED: m-tile k (gate type) covers gates 64k+16w+0..15
        b16x8 af[8];
#pragma unroll
        for (int k = 0; k < 4; ++k) {
            const int gate = 64 * k + 16 * w + mn;
            const float sck = (k == 2) ? -2.885390082f : -1.442695041f;
#pragma unroll
            for (int kh = 0; kh < 2; ++kh) {
                const float* ar = Whh + (size_t)gate * Hh + kh * 32 + q * 8;
                const float4 f0 = *(const float4*)ar;
                const float4 f1 = *(const float4*)(ar + 4);
                b16x8 a;
                a[0] = (__bf16)(f0.x * sck); a[1] = (__bf16)(f0.y * sck);
                a[2] = (__bf16)(f0.z * sck); a[3] = (__bf16)(f0.w * sck);
                a[4] = (__bf16)(f1.x * sck); a[5] = (__bf16)(f1.y * sck);
                a[6] = (__bf16)(f1.z * sck); a[7] = (__bf16)(f1.w * sck);
                af[2 * k + kh] = a;
            }
        }

        const int mi = lenp[(size_t)(b0 + row) * Hh + u_own];

        // seed h/c (zeros phase 0, gathered state phase 1) into buffer 0
        const float h0f = phase ? selh : 0.0f;
        c  = phase ? selc : 0.0f;
        cs = c * -2.885390082f;
        hsh[0][row][u_own] = (__bf16)h0f;
        selh = 0.0f; selc = 0.0f;
        __syncthreads();

        const float* tu = tab + 4 * u_own;

        // token register chunks: tkA = tokens[tb+4..7], tkB = tokens[tb+8..11]
        int4 tk0 = *(const int4*)&toklds[row][0];
        int4 tkA = *(const int4*)&toklds[row][4];
        int4 tkB = *(const int4*)&toklds[row][8];

        // prime S slots 0..3 (t=0..3); slots 4..7 are filled during steps 0..3
        f32x4 S0, S1, S2, S3, S4, S5, S6, S7;
        S0 = *(const f32x4*)(tu + (size_t)tk0.x * 256);
        S1 = *(const f32x4*)(tu + (size_t)tk0.y * 256);
        S2 = *(const f32x4*)(tu + (size_t)tk0.z * 256);
        S3 = *(const f32x4*)(tu + (size_t)tk0.w * 256);

        // select acc element rsel (2-bit, runtime) with static element indices
        auto pick = [&](const f32x4& a) -> float {
            const float e01 = sb0 ? a[1] : a[0];
            const float e23 = sb0 ? a[3] : a[2];
            return sb1 ? e23 : e01;
        };

        // step i: consume Su (slot i), refill Sf (slot (i+4)&7) with token tok
        auto step = [&](int i, f32x4& Su, f32x4& Sf, int tok, int tb) {
            // refill FIRST: register token -> address ready, no compute dep,
            // load issues at step start; consumed slot Su untouched.
            Sf = *(const f32x4*)(tu + (size_t)tok * 256);

            const int rb = i & 1, wb = rb ^ 1;
            const b16x8 bf0 = *(const b16x8*)&hsh[rb][row][q * 8];
            const b16x8 bf1 = *(const b16x8*)&hsh[rb][row][32 + q * 8];

            // order g,i,f,o: tanh(gG) is the longest dependent chain
            f32x4 aG = __builtin_amdgcn_mfma_f32_16x16x32_bf16(af[4], bf0, zero4, 0, 0, 0);
            aG = __builtin_amdgcn_mfma_f32_16x16x32_bf16(af[5], bf1, aG, 0, 0, 0);
            f32x4 aI = __builtin_amdgcn_mfma_f32_16x16x32_bf16(af[0], bf0, zero4, 0, 0, 0);
            aI = __builtin_amdgcn_mfma_f32_16x16x32_bf16(af[1], bf1, aI, 0, 0, 0);
            f32x4 aF = __builtin_amdgcn_mfma_f32_16x16x32_bf16(af[2], bf0, zero4, 0, 0, 0);
            aF = __builtin_amdgcn_mfma_f32_16x16x32_bf16(af[3], bf1, aF, 0, 0, 0);
            f32x4 aO = __builtin_amdgcn_mfma_f32_16x16x32_bf16(af[6], bf0, zero4, 0, 0, 0);
            aO = __builtin_amdgcn_mfma_f32_16x16x32_bf16(af[7], bf1, aO, 0, 0, 0);

            const float gG = pick(aG) + Su[2];
            const float gI = pick(aI) + Su[0];
            const float gF = pick(aF) + Su[1];
            const float gO = pick(aO) + Su[3];

            // g-gate: both plain and prescaled tanh derived from one rcp
            const float rg  = frcp(1.0f + fexp2(gG));       // gG prescaled by -2log2e
            const float gv  = 2.0f * rg - 1.0f;             // tanh(g)
            const float gvs = -5.770780164f * rg + 2.885390082f;  // -2log2e * tanh(g)
            const float iv = fsig_p(gI);
            const float fv = fsig_p(gF);
            const float ov = fsig_p(gO);
            c  = fv * c  + iv * gv;                         // true cell state
            cs = fv * cs + iv * gvs;                        // shadow: -2log2e * c
            const float th = 2.0f * frcp(1.0f + fexp2(cs)) - 1.0f;  // tanh(c), no mul
            const float hv = ov * th;
            hsh[wb][row][u_own] = (__bf16)hv;   // write first: off the tail
            barrier_novm();   // ONE barrier/step; global prefetch stays in flight
            if (tb + i == mi) { selh = hv; selc = c; }  // under next ds_read
        };

        for (int tb = 0; tb < Tt; tb += 8) {
            step(0, S0, S4, tkA.x, tb);
            step(1, S1, S5, tkA.y, tb);
            // next-iteration token chunks (ds_read latency hidden under steps)
            const int nb1 = min(tb + 12, Tt - 4);
            const int4 tA2 = *(const int4*)&toklds[row][nb1];
            step(2, S2, S6, tkA.z, tb);
            const int nb2 = min(tb + 16, Tt - 4);
            const int4 tB2 = *(const int4*)&toklds[row][nb2];
            step(3, S3, S7, tkA.w, tb);
            step(4, S4, S0, tkB.x, tb);
            step(5, S5, S1, tkB.y, tb);
            step(6, S6, S2, tkB.z, tb);
            step(7, S7, S3, tkB.w, tb);
            tkA = tA2; tkB = tB2;
        }
    }

    // ---------------- epilogue MLP on the 4 gathered rows -------------------
    h2s[row][u_own] = selh;
    __syncthreads();
#pragma unroll
    for (int p = 0; p < 2; ++p) {
        const int idx = tid + 256 * p;        // 512 (row, neuron) tasks
        const int rr = idx >> 7, n = idx & 127;
        float a = bl1[n];
        const float* wl = Wl1 + n * 64;
#pragma unroll 8
        for (int k = 0; k < 64; ++k) a += h2s[rr][k] * wl[k];
        ys[rr][n] = ftanh(a);
    }
    __syncthreads();
    if (tid < 16) {
        const int rr = tid >> 2, o = tid & 3;
        float a = bl2[o];
        const float* wl = Wl2 + o * 128;
#pragma unroll 8
        for (int k = 0; k < 128; ++k) a += ys[rr][k] * wl[k];
        out[(size_t)(b0 + rr) * 4 + o] = a;
    }
}

// ---------------------------------------------------------------------------
extern "C" void kernel_launch(void* const* d_in, const int* in_sizes, int n_in,
                              void* d_out, int out_size, void* d_ws, size_t ws_size,
                              hipStream_t stream) {
    const int*   s1   = (const int*)d_in[0];
    const int*   s2   = (const int*)d_in[1];
    const int*   l1   = (const int*)d_in[2];
    const int*   l2   = (const int*)d_in[3];
    // d_in[4], d_in[5] (s1_s, s2_s) unused by the reference
    const float* emb  = (const float*)d_in[6];
    const float* Wih1 = (const float*)d_in[7];
    const float* Whh1 = (const float*)d_in[8];
    const float* bih1 = (const float*)d_in[9];
    const float* bhh1 = (const float*)d_in[10];
    const float* Wih2 = (const float*)d_in[11];
    const float* Whh2 = (const float*)d_in[12];
    const float* bih2 = (const float*)d_in[13];
    const float* bhh2 = (const float*)d_in[14];
    const float* Wl1  = (const float*)d_in[15];
    const float* bl1  = (const float*)d_in[16];
    const float* Wl2  = (const float*)d_in[17];
    const float* bl2  = (const float*)d_in[18];
    float* out = (float*)d_out;

    float* tab1 = (float*)d_ws;                       // [V,256] fp32, unit-major
    float* tab2 = tab1 + (size_t)Vv * 256;            // [V,256] fp32  (65.6 MB)

    dim3 grid((Vv + MB - 1) / MB, 2);
    build_tables<<<grid, 256, 0, stream>>>(emb, Wih1, bih1, bhh1,
                                           Wih2, bih2, bhh2, tab1, tab2);
    lstm_main<<<Bsz / 4, 256, 0, stream>>>(s1, s2, l1, l2, tab1, tab2,
                                           Whh1, Whh2, Wl1, bl1, Wl2, bl2, out);
}